// Round 2
// 457.463 us; speedup vs baseline: 1.0982x; 1.0982x over previous
//
#include <hip/hip_runtime.h>
#include <cstdint>
#include <cstddef>

// Problem: D_OUT=32768, D_IN=1024, all fp32 inputs.
// total = sum(DW*Z) + lamb_reg*sum(1-(2Th-1)^2) + 0.05*4*sum_i (sum_j W*Z)^2
// where DW = W - s*(Q+Th), Z = DW @ Sigma^T  (Z[i,j] = sum_k DW[i,k]*Sigma[j,k])

#define DOUT 32768
#define DIN  1024
#define PREP_BLOCKS 2048
#define PREP_CHUNKS (DOUT / PREP_BLOCKS)   // 16 rows per block
#define PREP_G 4                           // chunks batched per load group (MLP)

typedef __bf16 bf16x8 __attribute__((ext_vector_type(8)));
typedef float  f32x4  __attribute__((ext_vector_type(4)));
typedef unsigned short u16x4 __attribute__((ext_vector_type(4)));

__device__ __forceinline__ unsigned short f2bf(float f) {
  union { float f; unsigned u; } v; v.f = f;
  unsigned u = v.u + 0x7fffu + ((v.u >> 16) & 1u);   // RNE
  return (unsigned short)(u >> 16);
}
__device__ __forceinline__ float bf2f(unsigned short b) {
  union { float f; unsigned u; } v; v.u = ((unsigned)b) << 16;
  return v.f;
}

// ---- Pass 1: DW = W - s*(Q+Th) in bf16; per-block binary-reg partial ----
// R2: closed-form tanh via v_exp+v_rcp (VALUBusy now 9%).
// R3: prep was latency/MLP-bound, not BW-bound (3.18 TB/s app vs 6.3 ceiling,
// VALUBusy 9%, VGPR=36 -> only ~1 chunk of loads in flight per wave).
// Fix: batch-issue PREP_G chunks of loads (12x dwordx4) before consuming;
// Q/Theta single-use -> nontemporal (preserve LLC for W+DW reused by gemm).
// Also folds the old sconv kernel in (blocks 0..1023 convert Sigma).
// R3b: nontemporal builtin needs clang ext_vector types, not HIP float4.
__global__ __launch_bounds__(256) void prep(
    const f32x4* __restrict__ W4, const f32x4* __restrict__ Q4,
    const f32x4* __restrict__ T4, const float* __restrict__ s,
    const f32x4* __restrict__ S4, u16x4* __restrict__ SB4,
    u16x4* __restrict__ DW4, float* __restrict__ bpart)
{
  const int tid = threadIdx.x;
  const int b   = blockIdx.x;

  // merged Sigma fp32 -> bf16 (1M elements = 262144 float4; blocks 0..1023)
  const int gi = b * 256 + tid;
  if (gi < (DIN * DIN) / 4) {
    f32x4 v = S4[gi];
    u16x4 o;
    o[0] = f2bf(v[0]); o[1] = f2bf(v[1]); o[2] = f2bf(v[2]); o[3] = f2bf(v[3]);
    SB4[gi] = o;
  }

  float bsum = 0.f;
#pragma unroll 1
  for (int g = 0; g < PREP_CHUNKS; g += PREP_G) {
    f32x4 wv[PREP_G], qv[PREP_G], tv[PREP_G];
    float sv[PREP_G];
    size_t idx[PREP_G];
#pragma unroll
    for (int u = 0; u < PREP_G; ++u) {
      const int row = b + (g + u) * PREP_BLOCKS;     // block-uniform
      idx[u] = (size_t)row * 256 + tid;              // 256 float4 per row
      wv[u] = W4[idx[u]];
      qv[u] = __builtin_nontemporal_load(&Q4[idx[u]]);
      tv[u] = __builtin_nontemporal_load(&T4[idx[u]]);
      sv[u] = s[row];
    }
#pragma unroll
    for (int u = 0; u < PREP_G; ++u) {
      u16x4 dp;
#pragma unroll
      for (int e = 0; e < 4; ++e) {
        float ex = __builtin_amdgcn_exp2f(tv[u][e] * 2.885390082f); // e^(2x)
        float th = 1.1f - 1.2f * __builtin_amdgcn_rcpf(ex + 1.f);
        th = fminf(fmaxf(th, 0.f), 1.f);
        float um = 2.f * th - 1.f;
        bsum += 1.f - um * um;
        dp[e] = f2bf(wv[u][e] - sv[u] * (qv[u][e] + th));
      }
      DW4[idx[u]] = dp;
    }
  }
  for (int off = 32; off; off >>= 1) bsum += __shfl_down(bsum, off);
  __shared__ float r4[4];
  if ((tid & 63) == 0) r4[tid >> 6] = bsum;
  __syncthreads();
  if (tid == 0) bpart[b] = r4[0] + r4[1] + r4[2] + r4[3];
}

// ---------------- Fused GEMM: Z = DW @ Sigma^T, epilogue reduces ----------------
// 128x128 tile, BK=64, 256 thr (4 waves, 2x2 wave grid, 64x64 each, 4x4 mfma 16x16x32)
// R2 fixes: (a) XOR swizzle: logical k-chunk c of row r lives at physical chunk
// c^(r&7); applied on the GLOBAL-read side since global_load_lds dst is
// lane-contiguous. Kills the 16-way read conflicts (2.5e7 cycles).
// (b) 1-D grid + XCD swizzle: the 8 n-blocks sharing a DW m-tile land on ONE
// XCD consecutively -> tile read once into its L2 instead of 8 HBM fetches.
__global__ __launch_bounds__(256, 4) void gemm_fused(
    const unsigned short* __restrict__ DW,   // [DOUT][DIN] bf16 bits
    const unsigned short* __restrict__ SG,   // [DIN][DIN]  bf16 bits (Sigma row-major = B^T layout)
    const float* __restrict__ Wf,            // [DOUT][DIN] fp32
    float* __restrict__ t_arr,               // [DOUT]
    float* __restrict__ acc)                 // scalar accumulator
{
  constexpr int K = DIN;
  const int lb  = blockIdx.x;                // 2048 blocks
  const int xcd = lb & 7;
  const int idx = lb >> 3;                   // 0..255
  const int m0  = (xcd * 32 + (idx >> 3)) * 128;
  const int n0  = (idx & 7) * 128;
  const int tid = threadIdx.x;
  const int w = tid >> 6;
  const int lane = tid & 63;
  const int wr = w >> 1, wc = w & 1;

  __shared__ unsigned short As[128 * 64];    // [row][k-chunk swizzled] 128B pitch
  __shared__ unsigned short Bs[128 * 64];
  __shared__ float red4[4];

  f32x4 accr[4][4];
#pragma unroll
  for (int i = 0; i < 4; ++i)
#pragma unroll
    for (int j = 0; j < 4; ++j) accr[i][j] = (f32x4){0.f, 0.f, 0.f, 0.f};

  const int l8 = lane >> 3;                     // sub-row within 1KB chunk (0..7)
  const int lc = ((lane & 7) ^ l8) << 3;        // swizzled k-element offset (8 bf16 = 16B)

  for (int kt = 0; kt < K / 64; ++kt) {
    const int k0 = kt * 64;
#pragma unroll
    for (int c = 0; c < 4; ++c) {
      const int sub  = c * 4 + w;               // 0..15 : which 1KB LDS chunk
      const int rowa = sub * 8 + l8;            // 0..127 tile row
      const int ldso = (sub * 64 + lane) * 8;   // element offset (lane*16B within chunk)
      const unsigned short* ga = DW + (size_t)(m0 + rowa) * K + (k0 + lc);
      const unsigned short* gb = SG + (size_t)(n0 + rowa) * K + (k0 + lc);
      __builtin_amdgcn_global_load_lds(
          (const __attribute__((address_space(1))) void*)ga,
          (__attribute__((address_space(3))) void*)(As + ldso), 16, 0, 0);
      __builtin_amdgcn_global_load_lds(
          (const __attribute__((address_space(1))) void*)gb,
          (__attribute__((address_space(3))) void*)(Bs + ldso), 16, 0, 0);
    }
    __syncthreads();

    {
      const int q   = lane >> 4;
      const int mr  = lane & 15;
      const int mr7 = mr & 7;
#pragma unroll
      for (int kk = 0; kk < 64; kk += 32) {
        bf16x8 af[4], bfr[4];
        const int cl  = (kk >> 3) + q;          // logical chunk (0..7)
        const int pc8 = ((cl ^ mr7) << 3);      // physical chunk offset, elements
#pragma unroll
        for (int ti = 0; ti < 4; ++ti)
          af[ti] = *(const bf16x8*)&As[(wr * 64 + ti * 16 + mr) * 64 + pc8];
#pragma unroll
        for (int tj = 0; tj < 4; ++tj)
          bfr[tj] = *(const bf16x8*)&Bs[(wc * 64 + tj * 16 + mr) * 64 + pc8];
#pragma unroll
        for (int ti = 0; ti < 4; ++ti)
#pragma unroll
          for (int tj = 0; tj < 4; ++tj)
            accr[ti][tj] = __builtin_amdgcn_mfma_f32_16x16x32_bf16(
                af[ti], bfr[tj], accr[ti][tj], 0, 0, 0);
      }
    }
    __syncthreads();
  }

  // Epilogue: C/D layout col=lane&15, row=(lane>>4)*4+reg
  const int q  = lane >> 4;
  const int cn = lane & 15;
  float actp = 0.f;
#pragma unroll
  for (int ti = 0; ti < 4; ++ti) {
#pragma unroll
    for (int r = 0; r < 4; ++r) {
      const int i = m0 + wr * 64 + ti * 16 + q * 4 + r;
      const float*          wrow  = Wf + (size_t)i * K;
      const unsigned short* dwrow = DW + (size_t)i * K;
      float ts = 0.f;
#pragma unroll
      for (int tj = 0; tj < 4; ++tj) {
        const int j = n0 + wc * 64 + tj * 16 + cn;
        const float z = accr[ti][tj][r];
        ts   = fmaf(wrow[j], z, ts);          // t_i partial
        actp = fmaf(bf2f(dwrow[j]), z, actp); // activation partial
      }
#pragma unroll
      for (int off = 8; off; off >>= 1) ts += __shfl_xor(ts, off, 16);
      if (cn == 0) atomicAdd(&t_arr[i], ts);
    }
  }
  for (int off = 32; off; off >>= 1) actp += __shfl_down(actp, off);
  if (lane == 0) red4[w] = actp;
  __syncthreads();
  if (tid == 0) atomicAdd(acc, red4[0] + red4[1] + red4[2] + red4[3]);
}

// ---------------- Final: out = acc + 0.2*sum(t_i^2) + 2e-4*sum(bpart) ----------------
// R3: float4 loads + full unroll (was scalar, single-block latency-bound).
__global__ __launch_bounds__(1024) void finish(const f32x4* __restrict__ t4,
                                               const f32x4* __restrict__ bp4,
                                               const float* __restrict__ acc,
                                               float* __restrict__ out)
{
  __shared__ float red[16];
  float g = 0.f;
#pragma unroll
  for (int it = 0; it < (DOUT / 4) / 1024; ++it) {   // 8 iterations
    f32x4 t = t4[it * 1024 + threadIdx.x];
    g = fmaf(0.2f * t[0], t[0], g);
    g = fmaf(0.2f * t[1], t[1], g);
    g = fmaf(0.2f * t[2], t[2], g);
    g = fmaf(0.2f * t[3], t[3], g);
  }
  if (threadIdx.x < PREP_BLOCKS / 4) {               // 512 float4 of bpart
    f32x4 bv = bp4[threadIdx.x];
    g = fmaf(2.0e-4f, (bv[0] + bv[1]) + (bv[2] + bv[3]), g);
  }
  for (int off = 32; off; off >>= 1) g += __shfl_down(g, off);
  if ((threadIdx.x & 63) == 0) red[threadIdx.x >> 6] = g;
  __syncthreads();
  if (threadIdx.x == 0) {
    float tot = 0.f;
#pragma unroll
    for (int i = 0; i < 16; ++i) tot += red[i];
    out[0] = acc[0] + tot;
  }
}

extern "C" void kernel_launch(void* const* d_in, const int* in_sizes, int n_in,
                              void* d_out, int out_size, void* d_ws, size_t ws_size,
                              hipStream_t stream) {
  const float* W     = (const float*)d_in[0];
  const float* Sigma = (const float*)d_in[1];
  const float* Q     = (const float*)d_in[2];
  const float* s     = (const float*)d_in[3];
  const float* Theta = (const float*)d_in[4];
  float* out = (float*)d_out;

  // ws layout: [0,256) acc | [256,+128K) t_arr | [+8K) bpart | [+2MB) Sigma bf16 | [+64MB) DW bf16
  char* ws = (char*)d_ws;
  float* acc   = (float*)ws;
  float* t_arr = (float*)(ws + 256);
  float* bpart = (float*)(ws + 256 + 131072);
  unsigned short* SigB = (unsigned short*)(ws + 256 + 131072 + 8192);
  unsigned short* DWb  = (unsigned short*)(ws + 256 + 131072 + 8192 + 2097152);

  (void)hipMemsetAsync(d_ws, 0, 256 + 131072, stream);  // zero acc + t_arr (ws poisoned 0xAA)

  prep<<<PREP_BLOCKS, 256, 0, stream>>>((const f32x4*)W, (const f32x4*)Q,
                                        (const f32x4*)Theta, s,
                                        (const f32x4*)Sigma, (u16x4*)SigB,
                                        (u16x4*)DWb, bpart);
  gemm_fused<<<2048, 256, 0, stream>>>(DWb, SigB, W, t_arr, acc);
  finish<<<1, 1024, 0, stream>>>((const f32x4*)t_arr, (const f32x4*)bpart, acc, out);
}